// Round 1
// baseline (167.801 us; speedup 1.0000x reference)
//
#include <hip/hip_runtime.h>

// MutexLoss: 8 images x 32 boxes; 100 fragment pts/box; 100 boundary pts/box.
// loss = mean_img( sum_{k,f,j!=k} [frag(k,f) inside box j] * min_b d2(frag(k,f), bnd(j,b)) / 3168 )

#define NIMG 8
#define KB   32
#define FPn  100
#define BPn  100

__device__ __forceinline__ float s25(int j) { return (j == 24) ? 1.0f : (float)j * (1.0f / 24.0f); }
__device__ __forceinline__ float s10f(int j) { return (j == 9) ? 1.0f : (float)j * (1.0f / 9.0f); }

__global__ __launch_bounds__(128) void mutex_loss_kernel(const float* __restrict__ boxes,
                                                         float* __restrict__ out) {
    const int blk = blockIdx.x;      // 0..255
    const int img = blk >> 5;        // image index
    const int k   = blk & 31;        // box index within image
    const int tid = threadIdx.x;     // 128 threads = 2 waves; lanes 0..99 hold frag pts

    __shared__ float ex0[KB], ey0[KB], ex1[KB], ey1[KB];
    __shared__ float bxs[KB][BPn];
    __shared__ float bys[KB][BPn];
    __shared__ float wsum[2];

    // Load this image's 32 boxes (centers -> extents), exactly like _centers_to_extents.
    if (tid < KB) {
        const float4 b = reinterpret_cast<const float4*>(boxes)[img * KB + tid];
        const float hx = b.z * 0.5f, hy = b.w * 0.5f;
        ex0[tid] = b.x - hx; ey0[tid] = b.y - hy;
        ex1[tid] = b.x + hx; ey1[tid] = b.y + hy;
    }
    __syncthreads();

    // Scaled boundary points for all 32 boxes of this image: 3200 pts.
    for (int p = tid; p < KB * BPn; p += 128) {
        const int j = p / BPn;
        const int b = p - j * BPn;
        float ux, uy;
        if (b < 50) {                     // meshgrid(two, s): (two[i], s[jj]), p = i*25+jj
            const int i = b / 25, jj = b - i * 25;
            ux = (float)i; uy = s25(jj);
        } else {                          // meshgrid(s, two): (s[i], two[jj]), q = i*2+jj
            const int q = b - 50;
            const int i = q >> 1;
            ux = s25(i); uy = (float)(q & 1);
        }
        const float w = ex1[j] - ex0[j];  // wh derived from extents, like the reference
        const float h = ey1[j] - ey0[j];
        bxs[j][b] = ux * w + ex0[j];
        bys[j][b] = uy * h + ey0[j];
    }
    __syncthreads();

    // Fragment point of box k owned by this lane.
    const bool active = (tid < FPn);
    float fx = 0.0f, fy = 0.0f;
    if (active) {
        const int fi = tid / 10, fj = tid - fi * 10;   // fragment[f] = (s[fi], s[fj])
        const float w = ex1[k] - ex0[k];
        const float h = ey1[k] - ey0[k];
        fx = s10f(fi) * w + ex0[k];
        fy = s10f(fj) * h + ey0[k];
    }

    float sum = 0.0f;
    for (int j = 0; j < KB; ++j) {
        // inclusive containment, matching (diff >= 0).sum(-1) == 4, j != k
        const bool in = active && (j != k) &&
                        (fx >= ex0[j]) && (fy >= ey0[j]) &&
                        (fx <= ex1[j]) && (fy <= ey1[j]);
        if (__any(in)) {                  // wave-coherent skip: containment is rare
            float m = 1e30f;
            const float* __restrict__ bxj = bxs[j];
            const float* __restrict__ byj = bys[j];
#pragma unroll 4
            for (int b = 0; b < BPn; ++b) {
                const float dx = fx - bxj[b];   // uniform LDS address -> broadcast, no conflict
                const float dy = fy - byj[b];
                m = fminf(m, dx * dx + dy * dy);
            }
            if (in) sum += m;
        }
    }

    // Block reduction: wave shuffle then 2-wave combine.
    for (int o = 32; o > 0; o >>= 1) sum += __shfl_down(sum, o);
    if ((tid & 63) == 0) wsum[tid >> 6] = sum;
    __syncthreads();
    if (tid == 0) {
        // per-image /(K*FP-K)=3168, mean over 8 images -> /25344
        atomicAdd(out, (wsum[0] + wsum[1]) * (1.0f / 25344.0f));
    }
}

extern "C" void kernel_launch(void* const* d_in, const int* in_sizes, int n_in,
                              void* d_out, int out_size, void* d_ws, size_t ws_size,
                              hipStream_t stream) {
    const float* boxes = (const float*)d_in[0];   // (256, 4) centers: xc, yc, w, h
    float* out = (float*)d_out;                   // scalar f32
    (void)d_ws; (void)ws_size; (void)in_sizes; (void)n_in; (void)out_size;

    hipMemsetAsync(out, 0, sizeof(float), stream);
    mutex_loss_kernel<<<256, 128, 0, stream>>>(boxes, out);
}

// Round 2
// 17.410 us; speedup vs baseline: 9.6380x; 9.6380x over previous
//
#include <hip/hip_runtime.h>

// MutexLoss: 8 images x 32 boxes; 100 fragment pts/box; 100 boundary pts/box.
// loss = mean_img( sum_{k,f,j!=k} [frag(k,f) inside box j] * min_b d2(frag(k,f), bnd(j,b)) / 3168 )
//
// Key optimization: boundary samples of box j lie on 4 edges with uniform
// spacing (25 samples/edge, endpoints exact). The min over the 100 sampled
// points is computed analytically: per edge, nearest-sample index =
// round(normalized coord * 24), reconstruct that sample position exactly as
// the reference does (s*wh + origin, s[24]=1.0), take min over 4 edges.
// Replaces a 100-iteration LDS latency-bound loop with ~30 register VALU ops.

#define KB   32
#define FPn  100

__device__ __forceinline__ float s25v(int j) { return (j == 24) ? 1.0f : (float)j * (1.0f / 24.0f); }
__device__ __forceinline__ float s10v(int j) { return (j == 9) ? 1.0f : (float)j * (1.0f / 9.0f); }

__global__ __launch_bounds__(128) void mutex_loss_kernel(const float* __restrict__ boxes,
                                                         float* __restrict__ out) {
    const int blk = blockIdx.x;      // 0..255
    const int img = blk >> 5;        // image index
    const int k   = blk & 31;        // box index within image
    const int tid = threadIdx.x;     // 128 threads; lanes 0..99 hold frag pts

    __shared__ float4 sbox[KB];      // x0, y0, x1, y1 (extents)
    __shared__ float2 sinv[KB];      // 24/w, 24/h
    __shared__ float  wsum[2];

    if (tid < KB) {
        const float4 b = reinterpret_cast<const float4*>(boxes)[img * KB + tid];
        const float hx = b.z * 0.5f, hy = b.w * 0.5f;
        const float x0 = b.x - hx, y0 = b.y - hy;
        const float x1 = b.x + hx, y1 = b.y + hy;
        sbox[tid] = make_float4(x0, y0, x1, y1);
        sinv[tid] = make_float2(24.0f / (x1 - x0), 24.0f / (y1 - y0));
    }
    __syncthreads();

    // Fragment point of box k owned by this lane: frag = s10 * wh + origin.
    const bool active = (tid < FPn);
    const float4 Bk = sbox[k];
    const float wk = Bk.z - Bk.x, hk = Bk.w - Bk.y;
    const int fi = tid / 10, fj = tid - fi * 10;
    const float fx = s10v(fi) * wk + Bk.x;
    const float fy = s10v(fj) * hk + Bk.y;

    float sum = 0.0f;
#pragma unroll
    for (int j = 0; j < KB; ++j) {
        const float4 B = sbox[j];        // uniform address -> broadcast
        const float2 I = sinv[j];
        const float w = B.z - B.x, h = B.w - B.y;

        // Vertical edges (x in {x0, x1}, y sampled at 25 points):
        int jy = __float2int_rn((fy - B.y) * I.y);
        jy = max(0, min(24, jy));
        const float sy  = s25v(jy) * h + B.y;    // reference's sample position
        const float dyv = fy - sy;
        const float dxl = fx - B.x, dxr = fx - B.z;
        const float d2a = fminf(dxl * dxl, dxr * dxr) + dyv * dyv;

        // Horizontal edges (y in {y0, y1}, x sampled at 25 points):
        int jx = __float2int_rn((fx - B.x) * I.x);
        jx = max(0, min(24, jx));
        const float sx  = s25v(jx) * w + B.x;
        const float dxh = fx - sx;
        const float dyb = fy - B.y, dyt = fy - B.w;
        const float d2b = fminf(dyb * dyb, dyt * dyt) + dxh * dxh;

        const float d2 = fminf(d2a, d2b);

        // Inclusive containment ((diff >= 0).sum == 4), excluding j == k.
        const bool in = active && (j != k) &&
                        (fx >= B.x) && (fy >= B.y) && (fx <= B.z) && (fy <= B.w);
        sum += in ? d2 : 0.0f;
    }

    // Block reduction: wave shuffle then 2-wave combine.
    for (int o = 32; o > 0; o >>= 1) sum += __shfl_down(sum, o);
    if ((tid & 63) == 0) wsum[tid >> 6] = sum;
    __syncthreads();
    if (tid == 0) {
        // per-image /(K*FP-K)=3168, mean over 8 images -> /25344
        atomicAdd(out, (wsum[0] + wsum[1]) * (1.0f / 25344.0f));
    }
}

extern "C" void kernel_launch(void* const* d_in, const int* in_sizes, int n_in,
                              void* d_out, int out_size, void* d_ws, size_t ws_size,
                              hipStream_t stream) {
    const float* boxes = (const float*)d_in[0];   // (256, 4) centers: xc, yc, w, h
    float* out = (float*)d_out;                   // scalar f32
    (void)d_ws; (void)ws_size; (void)in_sizes; (void)n_in; (void)out_size;

    hipMemsetAsync(out, 0, sizeof(float), stream);
    mutex_loss_kernel<<<256, 128, 0, stream>>>(boxes, out);
}

// Round 3
// 14.002 us; speedup vs baseline: 11.9839x; 1.2434x over previous
//
#include <hip/hip_runtime.h>

// MutexLoss: 8 images x 32 boxes; 100 fragment pts/box; 100 boundary pts/box.
// loss = mean_img( sum_{k,f,j!=k} [frag(k,f) inside box j] * min_b d2(frag(k,f), bnd(j,b)) / 3168 )
//
// Structure:
//  - kernel 1: 256 blocks (one per (img, k)); analytic nearest-boundary-sample
//    min (no 100-pt loop); block partial -> d_ws[blk] (plain store, no atomics).
//  - kernel 2: one 64-lane wave reduces the 256 partials and writes out[0].
//    Kernel boundary on the stream makes the partials coherent across XCDs.
//    No memset needed: out is overwritten with '=' every call.

#define KB   32
#define FPn  100

__device__ __forceinline__ float s25v(int j) { return (j == 24) ? 1.0f : (float)j * (1.0f / 24.0f); }
__device__ __forceinline__ float s10v(int j) { return (j == 9) ? 1.0f : (float)j * (1.0f / 9.0f); }

__global__ __launch_bounds__(128) void mutex_partial_kernel(const float* __restrict__ boxes,
                                                            float* __restrict__ partial) {
    const int blk = blockIdx.x;      // 0..255
    const int img = blk >> 5;        // image index
    const int k   = blk & 31;        // box index within image
    const int tid = threadIdx.x;     // 128 threads; lanes 0..99 hold frag pts

    __shared__ float4 sbox[KB];      // x0, y0, x1, y1 (extents)
    __shared__ float2 sinv[KB];      // 24/w, 24/h
    __shared__ float  wsum[2];

    if (tid < KB) {
        const float4 b = reinterpret_cast<const float4*>(boxes)[img * KB + tid];
        const float hx = b.z * 0.5f, hy = b.w * 0.5f;
        const float x0 = b.x - hx, y0 = b.y - hy;
        const float x1 = b.x + hx, y1 = b.y + hy;
        sbox[tid] = make_float4(x0, y0, x1, y1);
        sinv[tid] = make_float2(24.0f / (x1 - x0), 24.0f / (y1 - y0));
    }
    __syncthreads();

    // Fragment point of box k owned by this lane: frag = s10 * wh + origin.
    const bool active = (tid < FPn);
    const float4 Bk = sbox[k];
    const float wk = Bk.z - Bk.x, hk = Bk.w - Bk.y;
    const int fi = tid / 10, fj = tid - fi * 10;
    const float fx = s10v(fi) * wk + Bk.x;
    const float fy = s10v(fj) * hk + Bk.y;

    float sum = 0.0f;
#pragma unroll
    for (int j = 0; j < KB; ++j) {
        const float4 B = sbox[j];        // uniform address -> broadcast
        const float2 I = sinv[j];
        const float w = B.z - B.x, h = B.w - B.y;

        // Vertical edges (x in {x0, x1}, y sampled at 25 points):
        int jy = __float2int_rn((fy - B.y) * I.y);
        jy = max(0, min(24, jy));
        const float sy  = s25v(jy) * h + B.y;    // reference's exact sample position
        const float dyv = fy - sy;
        const float dxl = fx - B.x, dxr = fx - B.z;
        const float d2a = fminf(dxl * dxl, dxr * dxr) + dyv * dyv;

        // Horizontal edges (y in {y0, y1}, x sampled at 25 points):
        int jx = __float2int_rn((fx - B.x) * I.x);
        jx = max(0, min(24, jx));
        const float sx  = s25v(jx) * w + B.x;
        const float dxh = fx - sx;
        const float dyb = fy - B.y, dyt = fy - B.w;
        const float d2b = fminf(dyb * dyb, dyt * dyt) + dxh * dxh;

        const float d2 = fminf(d2a, d2b);

        // Inclusive containment ((diff >= 0).sum == 4), excluding j == k.
        const bool in = active && (j != k) &&
                        (fx >= B.x) && (fy >= B.y) && (fx <= B.z) && (fy <= B.w);
        sum += in ? d2 : 0.0f;
    }

    // Block reduction: wave shuffle then 2-wave combine; plain store, no atomic.
    for (int o = 32; o > 0; o >>= 1) sum += __shfl_down(sum, o);
    if ((tid & 63) == 0) wsum[tid >> 6] = sum;
    __syncthreads();
    if (tid == 0) partial[blk] = wsum[0] + wsum[1];
}

__global__ __launch_bounds__(64) void mutex_reduce_kernel(const float* __restrict__ partial,
                                                          float* __restrict__ out) {
    const int lane = threadIdx.x;    // single wave: 64 lanes x float4 = 256 partials
    const float4 v = reinterpret_cast<const float4*>(partial)[lane];
    float s = (v.x + v.y) + (v.z + v.w);
    for (int o = 32; o > 0; o >>= 1) s += __shfl_down(s, o);
    if (lane == 0) out[0] = s * (1.0f / 25344.0f);  // /(K*FP-K)=3168, /8 images
}

extern "C" void kernel_launch(void* const* d_in, const int* in_sizes, int n_in,
                              void* d_out, int out_size, void* d_ws, size_t ws_size,
                              hipStream_t stream) {
    const float* boxes = (const float*)d_in[0];   // (256, 4) centers: xc, yc, w, h
    float* out = (float*)d_out;                   // scalar f32
    float* partial = (float*)d_ws;                // 256 floats of scratch
    (void)ws_size; (void)in_sizes; (void)n_in; (void)out_size;

    mutex_partial_kernel<<<256, 128, 0, stream>>>(boxes, partial);
    mutex_reduce_kernel<<<1, 64, 0, stream>>>(partial, out);
}